// Round 1
// baseline (197.400 us; speedup 1.0000x reference)
//
#include <hip/hip_runtime.h>
#include <math.h>

#define NB 8192      // batch rows
#define NC 1000      // classes
#define NF4 250      // NC / 4 float4s per row

// ws layout (floats, stride NB):
//  [0..4]   margin per branch
//  [5..9]   gathered (raw) per branch
//  [10..14] KD per branch
//  [15]     CE
//  [16]     row min of gathered over 4 real teachers
//  [17]     row max of row-maxes over 4 real teachers
// total 18 * 8192 * 4 B = 576 KB of d_ws

__device__ __forceinline__ float wredsum(float v) {
#pragma unroll
  for (int m = 32; m >= 1; m >>= 1) v += __shfl_xor(v, m, 64);
  return v;
}
__device__ __forceinline__ float wredmax(float v) {
#pragma unroll
  for (int m = 32; m >= 1; m >>= 1) v = fmaxf(v, __shfl_xor(v, m, 64));
  return v;
}
__device__ __forceinline__ float wredmin(float v) {
#pragma unroll
  for (int m = 32; m >= 1; m >>= 1) v = fminf(v, __shfl_xor(v, m, 64));
  return v;
}
__device__ __forceinline__ void wredtop2(float& t1, float& t2) {
#pragma unroll
  for (int m = 32; m >= 1; m >>= 1) {
    float o1 = __shfl_xor(t1, m, 64);
    float o2 = __shfl_xor(t2, m, 64);
    float lo = fminf(t1, o1);
    t1 = fmaxf(t1, o1);
    t2 = fmaxf(fmaxf(t2, o2), lo);
  }
}
__device__ __forceinline__ float f4get(const float4& v, int e) {
  return e == 0 ? v.x : e == 1 ? v.y : e == 2 ? v.z : v.w;
}

// One wave (64 lanes) per row; 4 waves per block.
__global__ __launch_bounds__(256) void k_rowstats(
    const float* __restrict__ o1, const float* __restrict__ o2,
    const float* __restrict__ o3, const float* __restrict__ o4,
    const float* __restrict__ os, const int* __restrict__ tg,
    float* __restrict__ ws) {
  const int lane = threadIdx.x & 63;
  const int row = blockIdx.x * 4 + (threadIdx.x >> 6);

  const float4* p1 = (const float4*)(o1 + (size_t)row * NC);
  const float4* p2 = (const float4*)(o2 + (size_t)row * NC);
  const float4* p3 = (const float4*)(o3 + (size_t)row * NC);
  const float4* p4 = (const float4*)(o4 + (size_t)row * NC);
  const float4* ps = (const float4*)(os + (size_t)row * NC);

  float4 a1[4], a2[4], a3[4], a4[4], asv[4];
  const float4 NEG4 = make_float4(-INFINITY, -INFINITY, -INFINITY, -INFINITY);
#pragma unroll
  for (int j = 0; j < 4; ++j) {
    int f = j * 64 + lane;
    if (f < NF4) {
      a1[j] = p1[f]; a2[j] = p2[f]; a3[j] = p3[f]; a4[j] = p4[f]; asv[j] = ps[f];
    } else {
      a1[j] = NEG4; a2[j] = NEG4; a3[j] = NEG4; a4[j] = NEG4; asv[j] = NEG4;
    }
  }

  // ---- pass 1: top-2 per teacher (incl. mimic) + student max ----
  float t1[5], t2[5];
#pragma unroll
  for (int t = 0; t < 5; ++t) { t1[t] = -INFINITY; t2[t] = -INFINITY; }
  float ms = -INFINITY;

#pragma unroll
  for (int j = 0; j < 4; ++j) {
#pragma unroll
    for (int e = 0; e < 4; ++e) {
      float w0 = f4get(a1[j], e);
      float w1 = f4get(a2[j], e);
      float w2 = f4get(a3[j], e);
      float w3 = f4get(a4[j], e);
      float wsv = f4get(asv[j], e);
      float wm = ((w0 + w1) + w2 + w3) * 0.25f;   // mimic — keep this exact op order
      float w[5] = {w0, w1, w2, w3, wm};
#pragma unroll
      for (int t = 0; t < 5; ++t) {
        t2[t] = fmaxf(t2[t], fminf(t1[t], w[t]));
        t1[t] = fmaxf(t1[t], w[t]);
      }
      ms = fmaxf(ms, wsv);
    }
  }
#pragma unroll
  for (int t = 0; t < 5; ++t) wredtop2(t1[t], t2[t]);
  ms = wredmax(ms);

  // ---- pass 2 (registers): softmax sums at T=20 + KD cross term ----
  const float K20 = 1.4426950408889634f / 20.0f;  // log2(e)/20
  float Z[5] = {0.f, 0.f, 0.f, 0.f, 0.f};
  float S1[5] = {0.f, 0.f, 0.f, 0.f, 0.f};
  float Z1 = 0.f, Z20 = 0.f;
#pragma unroll
  for (int j = 0; j < 4; ++j) {
    if (j * 64 + lane < NF4) {
#pragma unroll
      for (int e = 0; e < 4; ++e) {
        float w0 = f4get(a1[j], e);
        float w1 = f4get(a2[j], e);
        float w2 = f4get(a3[j], e);
        float w3 = f4get(a4[j], e);
        float wsv = f4get(asv[j], e);
        float wm = ((w0 + w1) + w2 + w3) * 0.25f;
        float w[5] = {w0, w1, w2, w3, wm};
#pragma unroll
        for (int t = 0; t < 5; ++t) {
          float et = exp2f((w[t] - t1[t]) * K20);
          Z[t] += et;
          S1[t] += et * (w[t] - wsv);
        }
        Z1 += exp2f((wsv - ms) * 1.4426950408889634f);
        Z20 += exp2f((wsv - ms) * K20);
      }
    }
  }
#pragma unroll
  for (int t = 0; t < 5; ++t) { Z[t] = wredsum(Z[t]); S1[t] = wredsum(S1[t]); }
  Z1 = wredsum(Z1);
  Z20 = wredsum(Z20);

  if (lane == 0) {
    const int target = tg[row];
    const float g1 = (o1 + (size_t)row * NC)[target];
    const float g2 = (o2 + (size_t)row * NC)[target];
    const float g3 = (o3 + (size_t)row * NC)[target];
    const float g4 = (o4 + (size_t)row * NC)[target];
    const float gs = (os + (size_t)row * NC)[target];
    const float gm = ((g1 + g2) + g3 + g4) * 0.25f;  // same op order as wm
    float gg[5] = {g1, g2, g3, g4, gm};

    const float lse_s = ms * 0.05f + logf(Z20);   // logsumexp(out_s/20)
    const float CE = ms + logf(Z1) - gs;          // -log_softmax(out_s)[target]

#pragma unroll
    for (int t = 0; t < 5; ++t) {
      float lse_t = t1[t] * 0.05f + logf(Z[t]);
      float KD = 400.0f * (S1[t] / (20.0f * Z[t]) - lse_t + lse_s);
      float margin = (t1[t] == gg[t]) ? (t1[t] - t2[t]) : 0.0f;
      ws[(size_t)t * NB + row] = margin;
      ws[(size_t)(5 + t) * NB + row] = gg[t];
      ws[(size_t)(10 + t) * NB + row] = KD;
    }
    ws[(size_t)15 * NB + row] = CE;
    ws[(size_t)16 * NB + row] = fminf(fminf(g1, g2), fminf(g3, g4));
    ws[(size_t)17 * NB + row] = fmaxf(fmaxf(t1[0], t1[1]), fmaxf(t1[2], t1[3]));
  }
}

// Single block: global min/max -> shift & max_preds, then final weighted mean.
__global__ __launch_bounds__(1024) void k_final(const float* __restrict__ ws,
                                                float* __restrict__ out) {
  const int tid = threadIdx.x;
  const int lane = tid & 63, wv = tid >> 6;
  __shared__ float sA[16], sB[16];
  __shared__ float s_shift, s_maxp;

  float mn = INFINITY, mx = -INFINITY;
  for (int r = tid; r < NB; r += 1024) {
    mn = fminf(mn, ws[(size_t)16 * NB + r]);
    mx = fmaxf(mx, ws[(size_t)17 * NB + r]);
  }
  mn = wredmin(mn);
  mx = wredmax(mx);
  if (lane == 0) { sA[wv] = mn; sB[wv] = mx; }
  __syncthreads();
  if (tid == 0) {
    float a = sA[0], b = sB[0];
    for (int i = 1; i < 16; ++i) { a = fminf(a, sA[i]); b = fmaxf(b, sB[i]); }
    float shift = (a < 0.0f) ? (-a + 1e-5f) : 0.0f;
    s_shift = shift;
    s_maxp = b + shift;
  }
  __syncthreads();
  const float shift = s_shift;
  const float maxp = s_maxp;
  const float K6 = 1.4426950408889634f / 6.0f;

  float acc = 0.0f;
  for (int r = tid; r < NB; r += 1024) {
    float m[5], e[5];
#pragma unroll
    for (int t = 0; t < 5; ++t) m[t] = ws[(size_t)t * NB + r];
    float pm = fmaxf(fmaxf(fmaxf(m[0], m[1]), fmaxf(m[2], m[3])), m[4]);
    float Zl = 0.0f;
#pragma unroll
    for (int t = 0; t < 5; ++t) { e[t] = exp2f((m[t] - pm) * K6); Zl += e[t]; }
    float ce = ws[(size_t)15 * NB + r];
    float rl = 0.0f;
#pragma unroll
    for (int t = 0; t < 5; ++t) {
      float g = ws[(size_t)(5 + t) * NB + r];
      float kd = ws[(size_t)(10 + t) * NB + r];
      float w2 = (g + shift) / maxp;
      float loss = (1.0f - w2) * ce + w2 * kd;
      rl += e[t] * loss;
    }
    acc += rl / Zl;
  }
  acc = wredsum(acc);
  __syncthreads();   // sA reuse
  if (lane == 0) sA[wv] = acc;
  __syncthreads();
  if (tid == 0) {
    float tot = 0.0f;
    for (int i = 0; i < 16; ++i) tot += sA[i];
    out[0] = tot / 8192.0f;
  }
}

extern "C" void kernel_launch(void* const* d_in, const int* in_sizes, int n_in,
                              void* d_out, int out_size, void* d_ws, size_t ws_size,
                              hipStream_t stream) {
  const float* o1 = (const float*)d_in[0];
  const float* o2 = (const float*)d_in[1];
  const float* o3 = (const float*)d_in[2];
  const float* o4 = (const float*)d_in[3];
  const float* os = (const float*)d_in[4];
  const int* tg = (const int*)d_in[5];
  float* ws = (float*)d_ws;
  float* out = (float*)d_out;

  k_rowstats<<<NB / 4, 256, 0, stream>>>(o1, o2, o3, o4, os, tg, ws);
  k_final<<<1, 1024, 0, stream>>>(ws, out);
}

// Round 2
// 189.244 us; speedup vs baseline: 1.0431x; 1.0431x over previous
//
#include <hip/hip_runtime.h>
#include <math.h>

#define NB 8192      // batch rows
#define NC 1000      // classes
#define NF4 250      // NC / 4 float4s per row

// ws layout (floats, stride NB):
//  [0..4]   margin per branch
//  [5..9]   gathered (raw) per branch
//  [10..14] KD per branch
//  [15]     CE
//  [16]     row min of gathered over 4 real teachers
//  [17]     row max of row-maxes over 4 real teachers
//  [18*NB]     shift   (written by k_minmax)
//  [18*NB + 1] maxp    (written by k_minmax)
// total 18 * 8192 * 4 B + 8 B of d_ws

#define LOG2E 1.4426950408889634f
#define LN2   0.6931471805599453f

__device__ __forceinline__ float fexp2(float x) { return __builtin_amdgcn_exp2f(x); }
__device__ __forceinline__ float flog2(float x) { return __builtin_amdgcn_logf(x); }

__device__ __forceinline__ float wredsum(float v) {
#pragma unroll
  for (int m = 32; m >= 1; m >>= 1) v += __shfl_xor(v, m, 64);
  return v;
}
__device__ __forceinline__ float wredmax(float v) {
#pragma unroll
  for (int m = 32; m >= 1; m >>= 1) v = fmaxf(v, __shfl_xor(v, m, 64));
  return v;
}
__device__ __forceinline__ float wredmin(float v) {
#pragma unroll
  for (int m = 32; m >= 1; m >>= 1) v = fminf(v, __shfl_xor(v, m, 64));
  return v;
}
__device__ __forceinline__ void wredtop2(float& t1, float& t2) {
#pragma unroll
  for (int m = 32; m >= 1; m >>= 1) {
    float o1 = __shfl_xor(t1, m, 64);
    float o2 = __shfl_xor(t2, m, 64);
    float lo = fminf(t1, o1);
    t1 = fmaxf(t1, o1);
    t2 = fmaxf(fmaxf(t2, o2), lo);
  }
}
__device__ __forceinline__ float f4get(const float4& v, int e) {
  return e == 0 ? v.x : e == 1 ? v.y : e == 2 ? v.z : v.w;
}

// One wave (64 lanes) per row; 4 waves per block.
__global__ __launch_bounds__(256) void k_rowstats(
    const float* __restrict__ o1, const float* __restrict__ o2,
    const float* __restrict__ o3, const float* __restrict__ o4,
    const float* __restrict__ os, const int* __restrict__ tg,
    float* __restrict__ ws) {
  const int lane = threadIdx.x & 63;
  const int row = blockIdx.x * 4 + (threadIdx.x >> 6);

  // ---- issue the (wave-uniform) target gathers FIRST so their two chained
  // latencies overlap the main compute instead of serializing at the end ----
  const int target = tg[row];
  const float g1 = (o1 + (size_t)row * NC)[target];
  const float g2 = (o2 + (size_t)row * NC)[target];
  const float g3 = (o3 + (size_t)row * NC)[target];
  const float g4 = (o4 + (size_t)row * NC)[target];
  const float gs = (os + (size_t)row * NC)[target];

  const float4* p1 = (const float4*)(o1 + (size_t)row * NC);
  const float4* p2 = (const float4*)(o2 + (size_t)row * NC);
  const float4* p3 = (const float4*)(o3 + (size_t)row * NC);
  const float4* p4 = (const float4*)(o4 + (size_t)row * NC);
  const float4* ps = (const float4*)(os + (size_t)row * NC);

  float4 a1[4], a2[4], a3[4], a4[4], asv[4];
  const float4 NEG4 = make_float4(-INFINITY, -INFINITY, -INFINITY, -INFINITY);
#pragma unroll
  for (int j = 0; j < 4; ++j) {
    int f = j * 64 + lane;
    if (f < NF4) {
      a1[j] = p1[f]; a2[j] = p2[f]; a3[j] = p3[f]; a4[j] = p4[f]; asv[j] = ps[f];
    } else {
      a1[j] = NEG4; a2[j] = NEG4; a3[j] = NEG4; a4[j] = NEG4; asv[j] = NEG4;
    }
  }

  // ---- pass 1: top-2 per teacher (incl. mimic) + student max ----
  float t1[5], t2[5];
#pragma unroll
  for (int t = 0; t < 5; ++t) { t1[t] = -INFINITY; t2[t] = -INFINITY; }
  float ms = -INFINITY;

#pragma unroll
  for (int j = 0; j < 4; ++j) {
#pragma unroll
    for (int e = 0; e < 4; ++e) {
      float w0 = f4get(a1[j], e);
      float w1 = f4get(a2[j], e);
      float w2 = f4get(a3[j], e);
      float w3 = f4get(a4[j], e);
      float wsv = f4get(asv[j], e);
      float wm = ((w0 + w1) + w2 + w3) * 0.25f;   // mimic — keep this exact op order
      float w[5] = {w0, w1, w2, w3, wm};
#pragma unroll
      for (int t = 0; t < 5; ++t) {
        t2[t] = fmaxf(t2[t], fminf(t1[t], w[t]));
        t1[t] = fmaxf(t1[t], w[t]);
      }
      ms = fmaxf(ms, wsv);
    }
  }
#pragma unroll
  for (int t = 0; t < 5; ++t) wredtop2(t1[t], t2[t]);
  ms = wredmax(ms);

  // ---- pass 2 (registers): softmax sums at T=20 + KD cross term ----
  const float K20 = LOG2E / 20.0f;
  float Z[5] = {0.f, 0.f, 0.f, 0.f, 0.f};
  float S1[5] = {0.f, 0.f, 0.f, 0.f, 0.f};
  float Z1 = 0.f, Z20 = 0.f;
#pragma unroll
  for (int j = 0; j < 4; ++j) {
    if (j * 64 + lane < NF4) {
#pragma unroll
      for (int e = 0; e < 4; ++e) {
        float w0 = f4get(a1[j], e);
        float w1 = f4get(a2[j], e);
        float w2 = f4get(a3[j], e);
        float w3 = f4get(a4[j], e);
        float wsv = f4get(asv[j], e);
        float wm = ((w0 + w1) + w2 + w3) * 0.25f;
        float w[5] = {w0, w1, w2, w3, wm};
#pragma unroll
        for (int t = 0; t < 5; ++t) {
          float et = fexp2((w[t] - t1[t]) * K20);
          Z[t] += et;
          S1[t] += et * (w[t] - wsv);
        }
        Z1 += fexp2((wsv - ms) * LOG2E);
        Z20 += fexp2((wsv - ms) * K20);
      }
    }
  }
#pragma unroll
  for (int t = 0; t < 5; ++t) { Z[t] = wredsum(Z[t]); S1[t] = wredsum(S1[t]); }
  Z1 = wredsum(Z1);
  Z20 = wredsum(Z20);

  if (lane == 0) {
    const float gm = ((g1 + g2) + g3 + g4) * 0.25f;  // same op order as wm
    float gg[5] = {g1, g2, g3, g4, gm};

    const float lse_s = ms * 0.05f + flog2(Z20) * LN2;   // logsumexp(out_s/20)
    const float CE = ms + flog2(Z1) * LN2 - gs;          // -log_softmax(out_s)[target]

#pragma unroll
    for (int t = 0; t < 5; ++t) {
      float lse_t = t1[t] * 0.05f + flog2(Z[t]) * LN2;
      float KD = 400.0f * (S1[t] / (20.0f * Z[t]) - lse_t + lse_s);
      float margin = (t1[t] == gg[t]) ? (t1[t] - t2[t]) : 0.0f;
      ws[(size_t)t * NB + row] = margin;
      ws[(size_t)(5 + t) * NB + row] = gg[t];
      ws[(size_t)(10 + t) * NB + row] = KD;
    }
    ws[(size_t)15 * NB + row] = CE;
    ws[(size_t)16 * NB + row] = fminf(fminf(g1, g2), fminf(g3, g4));
    ws[(size_t)17 * NB + row] = fmaxf(fmaxf(t1[0], t1[1]), fmaxf(t1[2], t1[3]));
  }
}

// Single block: global min/max -> shift & max_preds; also zeroes out[0].
// Touches only 64 KB (the two row-reduced arrays) — fast despite 1 CU.
__global__ __launch_bounds__(1024) void k_minmax(float* __restrict__ ws,
                                                 float* __restrict__ out) {
  const int tid = threadIdx.x;
  const int lane = tid & 63, wv = tid >> 6;
  __shared__ float sA[16], sB[16];

  float mn = INFINITY, mx = -INFINITY;
  for (int r = tid; r < NB; r += 1024) {
    mn = fminf(mn, ws[(size_t)16 * NB + r]);
    mx = fmaxf(mx, ws[(size_t)17 * NB + r]);
  }
  mn = wredmin(mn);
  mx = wredmax(mx);
  if (lane == 0) { sA[wv] = mn; sB[wv] = mx; }
  __syncthreads();
  if (tid == 0) {
    float a = sA[0], b = sB[0];
    for (int i = 1; i < 16; ++i) { a = fminf(a, sA[i]); b = fmaxf(b, sB[i]); }
    float shift = (a < 0.0f) ? (-a + 1e-5f) : 0.0f;
    ws[(size_t)18 * NB] = shift;
    ws[(size_t)18 * NB + 1] = b + shift;
    out[0] = 0.0f;
  }
}

// Multi-block weighted-loss reduction; one atomicAdd per block.
__global__ __launch_bounds__(256) void k_loss(const float* __restrict__ ws,
                                              float* __restrict__ out) {
  const int tid = threadIdx.x;
  const int lane = tid & 63, wv = tid >> 6;
  const int r = blockIdx.x * 256 + tid;   // 32 blocks x 256 = 8192 rows
  __shared__ float sA[4];

  const float shift = ws[(size_t)18 * NB];
  const float maxp = ws[(size_t)18 * NB + 1];
  const float K6 = LOG2E / 6.0f;

  float m[5], e[5];
#pragma unroll
  for (int t = 0; t < 5; ++t) m[t] = ws[(size_t)t * NB + r];
  float pm = fmaxf(fmaxf(fmaxf(m[0], m[1]), fmaxf(m[2], m[3])), m[4]);
  float Zl = 0.0f;
#pragma unroll
  for (int t = 0; t < 5; ++t) { e[t] = fexp2((m[t] - pm) * K6); Zl += e[t]; }
  float ce = ws[(size_t)15 * NB + r];
  float rl = 0.0f;
#pragma unroll
  for (int t = 0; t < 5; ++t) {
    float g = ws[(size_t)(5 + t) * NB + r];
    float kd = ws[(size_t)(10 + t) * NB + r];
    float w2 = (g + shift) / maxp;
    float loss = (1.0f - w2) * ce + w2 * kd;
    rl += e[t] * loss;
  }
  float acc = rl / Zl;

  acc = wredsum(acc);
  if (lane == 0) sA[wv] = acc;
  __syncthreads();
  if (tid == 0) {
    float tot = (sA[0] + sA[1]) + (sA[2] + sA[3]);
    atomicAdd(out, tot * (1.0f / 8192.0f));
  }
}

extern "C" void kernel_launch(void* const* d_in, const int* in_sizes, int n_in,
                              void* d_out, int out_size, void* d_ws, size_t ws_size,
                              hipStream_t stream) {
  const float* o1 = (const float*)d_in[0];
  const float* o2 = (const float*)d_in[1];
  const float* o3 = (const float*)d_in[2];
  const float* o4 = (const float*)d_in[3];
  const float* os = (const float*)d_in[4];
  const int* tg = (const int*)d_in[5];
  float* ws = (float*)d_ws;
  float* out = (float*)d_out;

  k_rowstats<<<NB / 4, 256, 0, stream>>>(o1, o2, o3, o4, os, tg, ws);
  k_minmax<<<1, 1024, 0, stream>>>(ws, out);
  k_loss<<<NB / 256, 256, 0, stream>>>(ws, out);
}